// Round 1
// baseline (95.565 us; speedup 1.0000x reference)
//
#include <hip/hip_runtime.h>

// Problem constants (from reference)
#define B        8192
#define N_IN     8
#define N_MFS    4
#define N_RULES  2048

#define THREADS  256
#define NB       8          // batches per block
#define LUT_STRIDE 104      // floats per batch pair-LUT (100 used + pad)

// ---------------------------------------------------------------------------
// Pack kernel: for each rule, pack 4 pair-indices as bytes.
// byte p = 4 * (ia*5 + ib), where ia = mf[r][2p]  (-1 -> 4 = "masked, use 1.0")
// Pre-scaled by 4 so it is directly a byte offset into the pair LUT region.
// ---------------------------------------------------------------------------
__global__ void pack_rules(const int* __restrict__ mf, unsigned int* __restrict__ pk) {
    int r = blockIdx.x * blockDim.x + threadIdx.x;
    if (r >= N_RULES) return;
    unsigned int v = 0;
#pragma unroll
    for (int p = 0; p < 4; ++p) {
        int ia = mf[r * N_IN + 2 * p];
        int ib = mf[r * N_IN + 2 * p + 1];
        unsigned int a = (ia < 0) ? 4u : (unsigned int)ia;
        unsigned int b = (ib < 0) ? 4u : (unsigned int)ib;
        unsigned int byte = 4u * (a * 5u + b);   // <= 96, fits in a byte
        v |= byte << (8 * p);
    }
    pk[r] = v;
}

// ---------------------------------------------------------------------------
// Main kernel: each block handles NB batches x all 2048 rules.
// LDS: packed rules (8 KB) + per-batch pair-product LUTs (NB*104*4 B).
// Each thread computes 4 consecutive rules -> float4 store (fully coalesced).
// ---------------------------------------------------------------------------
__device__ __forceinline__ float rule_val(const char* lut_bytes, unsigned int pk) {
    // pair p's 25-float region starts at byte offset p*100 (compile-time imm)
    float v0 = *(const float*)(lut_bytes +   0 + (pk & 0xFFu));
    float v1 = *(const float*)(lut_bytes + 100 + ((pk >> 8) & 0xFFu));
    float v2 = *(const float*)(lut_bytes + 200 + ((pk >> 16) & 0xFFu));
    float v3 = *(const float*)(lut_bytes + 300 + (pk >> 24));
    return (v0 * v1) * (v2 * v3);
}

__global__ __launch_bounds__(THREADS) void fire_kernel(
        const float* __restrict__ x,
        const unsigned int* __restrict__ pk,
        float* __restrict__ out) {
    __shared__ unsigned int srules[N_RULES];
    __shared__ float slut[NB * LUT_STRIDE];

    const int tid = threadIdx.x;
    const int b0  = blockIdx.x * NB;

    // Stage packed rules: 2048 u32 = 512 uint4, 2 per thread, coalesced.
    {
        const uint4* g4 = (const uint4*)pk;
        uint4* s4 = (uint4*)srules;
#pragma unroll
        for (int i = tid; i < N_RULES / 4; i += THREADS) s4[i] = g4[i];
    }

    // Build pair-product LUTs: for each local batch, 4 pairs x 25 combos.
    // slut[bl*STRIDE + p*25 + a*5 + b] = va * vb  (index 4 -> 1.0)
    for (int e = tid; e < NB * 100; e += THREADS) {
        int bl   = e / 100;
        int rest = e - bl * 100;
        int p    = rest / 25;
        int c    = rest - p * 25;
        int a    = c / 5;
        int bb   = c - a * 5;
        const float* xb = x + (size_t)(b0 + bl) * (N_IN * N_MFS);
        float va = (a  < 4) ? xb[(2 * p)     * N_MFS + a ] : 1.0f;
        float vb = (bb < 4) ? xb[(2 * p + 1) * N_MFS + bb] : 1.0f;
        slut[bl * LUT_STRIDE + rest] = va * vb;
    }
    __syncthreads();

    // Compute: NB batches x 2048 rules; 4 rules per thread per pass, 2 passes.
#pragma unroll 1
    for (int bl = 0; bl < NB; ++bl) {
        const char* lutb = (const char*)(slut + bl * LUT_STRIDE);
        float* orow = out + (size_t)(b0 + bl) * N_RULES;
#pragma unroll
        for (int pass = 0; pass < 2; ++pass) {
            int r0 = pass * (THREADS * 4) + tid * 4;
            uint4 pkt = *(const uint4*)&srules[r0];
            float4 res;
            res.x = rule_val(lutb, pkt.x);
            res.y = rule_val(lutb, pkt.y);
            res.z = rule_val(lutb, pkt.z);
            res.w = rule_val(lutb, pkt.w);
            *(float4*)&orow[r0] = res;
        }
    }
}

extern "C" void kernel_launch(void* const* d_in, const int* in_sizes, int n_in,
                              void* d_out, int out_size, void* d_ws, size_t ws_size,
                              hipStream_t stream) {
    const float* x  = (const float*)d_in[0];       // (B, N_IN, N_MFS) fp32
    const int*   mf = (const int*)d_in[1];         // (N_RULES, N_IN) int32
    float* out = (float*)d_out;                    // (B, N_RULES) fp32
    unsigned int* pk = (unsigned int*)d_ws;        // 2048 * 4 B = 8 KB scratch

    pack_rules<<<(N_RULES + THREADS - 1) / THREADS, THREADS, 0, stream>>>(mf, pk);
    fire_kernel<<<B / NB, THREADS, 0, stream>>>(x, pk, out);
}

// Round 2
// 84.403 us; speedup vs baseline: 1.1322x; 1.1322x over previous
//
#include <hip/hip_runtime.h>

// Problem constants (from reference)
#define B        8192
#define N_IN     8
#define N_MFS    4
#define N_RULES  2048

#define THREADS  256
#define NB       8            // batches per block
#define LUT_W    101          // words per batch pair-LUT (100 used + 1 pad)

// One kernel. Per block: NB batches x all 2048 rules.
//  - Each thread packs its own 8 rules (2 passes x 4) from mf into 32
//    register-resident LDS byte offsets (pair*100 + 4*(a*5+b), a/b=4 -> masked).
//  - LDS holds only the per-batch pair-product LUTs (NB*101 words).
//  - Batch loop fully unrolled: ds_read_b32 vaddr = precomputed reg,
//    imm offset = bl*404 (+ pair base folded into the reg) -> no per-batch
//    address VALU. Gathers hit 25 consecutive words -> 25 distinct banks ->
//    conflict-free (same-word lanes broadcast).
//  - 4 rules/thread -> float4 coalesced stores (1 KB/wave-instr).
__global__ __launch_bounds__(THREADS) void fire_kernel(
        const float* __restrict__ x,
        const int*   __restrict__ mf,
        float* __restrict__ out)
{
    __shared__ float slut[NB * LUT_W];

    const int tid = threadIdx.x;
    const int b0  = blockIdx.x * NB;

    // ---- Pack this thread's 8 rules into 32 LDS byte addresses (registers).
    const char* lds_base = (const char*)slut;
    const char* ap[2][4][4];
#pragma unroll
    for (int pass = 0; pass < 2; ++pass) {
#pragma unroll
        for (int j = 0; j < 4; ++j) {
            const int r = pass * (THREADS * 4) + tid * 4 + j;
            const int4* mr = (const int4*)(mf + r * N_IN);
            const int4 lo = mr[0];
            const int4 hi = mr[1];
            const int idx[8] = {lo.x, lo.y, lo.z, lo.w, hi.x, hi.y, hi.z, hi.w};
#pragma unroll
            for (int p = 0; p < 4; ++p) {
                const unsigned int a = idx[2*p]   < 0 ? 4u : (unsigned int)idx[2*p];
                const unsigned int b = idx[2*p+1] < 0 ? 4u : (unsigned int)idx[2*p+1];
                ap[pass][j][p] = lds_base + (p * 100u + 4u * (a * 5u + b));
            }
        }
    }

    // ---- Build pair-product LUTs: slut[bl*101 + p*25 + a*5 + b] = va*vb.
    for (int e = tid; e < NB * 100; e += THREADS) {
        const int bl   = e / 100;
        const int rest = e - bl * 100;
        const int p    = rest / 25;
        const int c    = rest - p * 25;
        const int a    = c / 5;
        const int bb   = c - a * 5;
        const float* xb = x + (size_t)(b0 + bl) * (N_IN * N_MFS);
        const float va = (a  < 4) ? xb[(2*p)   * N_MFS + a ] : 1.0f;
        const float vb = (bb < 4) ? xb[(2*p+1) * N_MFS + bb] : 1.0f;
        slut[bl * LUT_W + rest] = va * vb;
    }
    __syncthreads();

    // ---- Main loop: fully unrolled, imm LDS offsets, coalesced float4 stores.
#pragma unroll
    for (int bl = 0; bl < NB; ++bl) {
        const unsigned int lo = bl * (LUT_W * 4);   // compile-time constant
#pragma unroll
        for (int pass = 0; pass < 2; ++pass) {
            float4 res;
            float* o = out + (size_t)(b0 + bl) * N_RULES + pass * (THREADS * 4) + tid * 4;
#pragma unroll
            for (int j = 0; j < 4; ++j) {
                const float v0 = *(const float*)(ap[pass][j][0] + lo);
                const float v1 = *(const float*)(ap[pass][j][1] + lo);
                const float v2 = *(const float*)(ap[pass][j][2] + lo);
                const float v3 = *(const float*)(ap[pass][j][3] + lo);
                const float r  = (v0 * v1) * (v2 * v3);
                if (j == 0) res.x = r;
                else if (j == 1) res.y = r;
                else if (j == 2) res.z = r;
                else res.w = r;
            }
            *(float4*)o = res;
        }
    }
}

extern "C" void kernel_launch(void* const* d_in, const int* in_sizes, int n_in,
                              void* d_out, int out_size, void* d_ws, size_t ws_size,
                              hipStream_t stream) {
    const float* x  = (const float*)d_in[0];   // (B, N_IN, N_MFS) fp32
    const int*   mf = (const int*)d_in[1];     // (N_RULES, N_IN) int32
    float* out = (float*)d_out;                // (B, N_RULES) fp32
    (void)d_ws; (void)ws_size;

    fire_kernel<<<B / NB, THREADS, 0, stream>>>(x, mf, out);
}